// Round 11
// baseline (156.339 us; speedup 1.0000x reference)
//
#include <hip/hip_runtime.h>

// B=16, Q=2048, K=2048, D=128, DV=128
// out[b,q,:] = softmax_k((q.k - 0.5||k||^2)/sqrt(192), mask k>=valid_len) @ V
// R19 = R18 (split jobs, grid 1024, disjoint-destination merge + norm) with
// the attn block made 3-blocks/CU resident. All schedules (R14/R17/R18) hit
// ~56us because per-tile latency doesn't improve when a block runs solo ->
// occupancy is the real lever, and LDS (65.5KB -> 2 blocks) was the cap.
// Change: K tile single-buffered (K frags are STREAMED into the S-MFMA chain,
// never held in regs -> no new register state, unlike R10/R13 which spilled).
// LDS 49.3KB -> 3 blocks/CU. Loop: syncthreads (tile ready) -> issue V/bias
// (double-buffered) -> stream S MFMA from Ksh -> lgkmcnt(0)+raw s_barrier
// (K reads done; V DMA stays in flight - NOT __syncthreads which drains
// vmcnt) -> issue K(next) into Ksh -> softmax+PV (hides K DMA). Epilogue
// slab overlays Ksh+Vsh (48KB >= 32KB needed).

#define Bn   16
#define Qn   2048
#define Kn   2048
#define Dn   128
#define DVn  128
#define BQ   64
#define BK   64

// (1/sqrt(192)) * log2(e) : softmax computed as 2^(qk*SC2 + bias2)
#define SC2 0.10411754f

typedef short bf16x4 __attribute__((ext_vector_type(4)));
typedef short bf16x8 __attribute__((ext_vector_type(8)));
typedef float f32x16 __attribute__((ext_vector_type(16)));

__device__ __forceinline__ short f2bf(float x) {   // RNE
    union { float f; unsigned u; } v; v.f = x;
    unsigned r = (v.u + 0x7fffu + ((v.u >> 16) & 1u)) >> 16;
    return (short)r;
}
__device__ __forceinline__ float bf2f(short h) {
    union { unsigned u; float f; } v; v.u = ((unsigned)(unsigned short)h) << 16;
    return v.f;
}

typedef const __attribute__((address_space(1))) void* gas_t;
typedef __attribute__((address_space(3))) void* las_t;
__device__ __forceinline__ void gld16(const void* g, void* l) {
    __builtin_amdgcn_global_load_lds((gas_t)g, (las_t)l, 16, 0, 0);
}
__device__ __forceinline__ void gld4(const void* g, void* l) {
    __builtin_amdgcn_global_load_lds((gas_t)g, (las_t)l, 4, 0, 0);
}
__device__ __forceinline__ float exp2_raw(float a) {  // D = 2^S0
    float p;
    asm("v_exp_f32 %0, %1" : "=v"(p) : "v"(a));
    return p;
}

// ---------- preprocess: K/V convert (coalesced) + per-batch q-sort ----------
__global__ __launch_bounds__(256) void prep_kv(const float* __restrict__ Kg,
                                               const float* __restrict__ Vg,
                                               const int* __restrict__ VLg,
                                               short* __restrict__ Kb,
                                               short* __restrict__ Vtb,
                                               float* __restrict__ biasg,
                                               int* __restrict__ perm) {
    const int tid = threadIdx.x;
    if (blockIdx.x < 1024) {
        // ---- K path: 32 rows (b*Kn+row flat) per block, fully coalesced ----
        const int rowbase = blockIdx.x * 32;
        const float* src = Kg + (size_t)rowbase * Dn;
        short*       dst = Kb + (size_t)rowbase * Dn;
#pragma unroll
        for (int p = 0; p < 4; ++p) {
            const int idx = p * 1024 + tid * 4;     // flat float index
            float4 x = *(const float4*)(src + idx);
            bf16x4 h;
            h[0] = f2bf(x.x); h[1] = f2bf(x.y); h[2] = f2bf(x.z); h[3] = f2bf(x.w);
            *(bf16x4*)(dst + idx) = h;
            float ssq = x.x*x.x + x.y*x.y + x.z*x.z + x.w*x.w;
            ssq += __shfl_xor(ssq, 1);
            ssq += __shfl_xor(ssq, 2);
            ssq += __shfl_xor(ssq, 4);
            ssq += __shfl_xor(ssq, 8);
            ssq += __shfl_xor(ssq, 16);
            if ((tid & 31) == 0)
                biasg[rowbase + p * 8 + (tid >> 5)] = -0.5f * ssq * SC2;
        }
    } else if (blockIdx.x < 1536) {
        // ---- V path: transpose one [64 k][128 v] tile to plain V^T bf16 ----
        const int blk = blockIdx.x - 1024;
        const int b  = blk >> 5;
        const int k0 = (blk & 31) * 64;
        __shared__ short Ls[64 * 128];
        // phase 1: coalesced float4 row reads; XOR-swizzled LDS writes
#pragma unroll
        for (int p = 0; p < 8; ++p) {
            const int kk = p * 8 + (tid >> 5);      // tile row 0..63
            const int v0 = (tid & 31) * 4;
            float4 x = *(const float4*)(Vg + ((size_t)b * Kn + k0 + kk) * DVn + v0);
            bf16x4 h;
            h[0] = f2bf(x.x); h[1] = f2bf(x.y); h[2] = f2bf(x.z); h[3] = f2bf(x.w);
            const int vs = v0 ^ ((kk & 15) << 3);   // keeps 4-short alignment
            *(bf16x4*)&Ls[kk * 128 + vs] = h;
        }
        __syncthreads();
        // phase 2: column gather (32 scalar reads) + coalesced 64B stores
        const int v = tid >> 1;
        const int h = (tid & 1) * 32;
        short* dst = Vtb + ((size_t)b * DVn + v) * Kn + k0 + h;
#pragma unroll
        for (int j4 = 0; j4 < 4; ++j4) {
            bf16x8 o;
#pragma unroll
            for (int j = 0; j < 8; ++j) {
                const int kk = h + j4 * 8 + j;
                o[j] = Ls[kk * 128 + (v ^ ((kk & 15) << 3))];
            }
            *(bf16x8*)(dst + j4 * 8) = o;
        }
    } else {
        // ---- sort path: counting sort of 2048 q-rows by valid_len, batch b ----
        const int b = blockIdx.x - 1536;
        __shared__ int hist[2048];
        __shared__ int part[256];
        int vq[8];
#pragma unroll
        for (int i = 0; i < 8; ++i) hist[i * 256 + tid] = 0;
        __syncthreads();
#pragma unroll
        for (int i = 0; i < 8; ++i) {
            vq[i] = VLg[b * Qn + i * 256 + tid];    // 1..2048
            atomicAdd(&hist[vq[i] - 1], 1);
        }
        __syncthreads();
        // exclusive scan over 2048 bins (8 per thread + block scan)
        int lex[8]; int s = 0;
#pragma unroll
        for (int j = 0; j < 8; ++j) { lex[j] = s; s += hist[tid * 8 + j]; }
        part[tid] = s;
        __syncthreads();
        for (int off = 1; off < 256; off <<= 1) {
            int v = (tid >= off) ? part[tid - off] : 0;
            __syncthreads();
            part[tid] += v;
            __syncthreads();
        }
        const int excl = part[tid] - s;
#pragma unroll
        for (int j = 0; j < 8; ++j) hist[tid * 8 + j] = excl + lex[j];
        __syncthreads();
        // scatter: ascending positions by valid_len
#pragma unroll
        for (int i = 0; i < 8; ++i) {
            const int pos = atomicAdd(&hist[vq[i] - 1], 1);
            perm[b * Qn + pos] = i * 256 + tid;
        }
    }
}

// epilogue helpers with LITERAL accumulator indices (no runtime Oacc[] index)
#define DUMP_ACC(ACC, DST)                                            \
    {                                                                 \
        _Pragma("unroll")                                             \
        for (int reg = 0; reg < 16; ++reg) {                          \
            const int row = (reg & 3) + 8 * (reg >> 2) + 4 * hi;      \
            (DST)[row * 32 + l31] = (ACC)[reg];                       \
        }                                                             \
    }
// raw fp32 partial -> Og (low half)
#define STORE_F(ACC, SRC, COLBASE)                                    \
    {                                                                 \
        _Pragma("unroll")                                             \
        for (int reg = 0; reg < 16; ++reg) {                          \
            const int row = (reg & 3) + 8 * (reg >> 2) + 4 * hi;      \
            Og_b[(size_t)permSh[pair * 32 + row] * DVn + (COLBASE) + l31] \
                = (ACC)[reg] + (SRC)[row * 32 + l31];                 \
        }                                                             \
    }
// raw bf16 partial -> P (high half)
#define STORE_H(ACC, SRC, COLBASE)                                    \
    {                                                                 \
        _Pragma("unroll")                                             \
        for (int reg = 0; reg < 16; ++reg) {                          \
            const int row = (reg & 3) + 8 * (reg >> 2) + 4 * hi;      \
            P_b[(size_t)permSh[pair * 32 + row] * DVn + (COLBASE) + l31] \
                = f2bf((ACC)[reg] + (SRC)[row * 32 + l31]);           \
        }                                                             \
    }

// ---------- main attention kernel (single-K-buffer, 3 blocks/CU) ----------
__global__ __launch_bounds__(256, 3) void attn_kernel(
    const float* __restrict__ Qg, const short* __restrict__ Kb,
    const short* __restrict__ Vtb, const float* __restrict__ biasg,
    const int* __restrict__ VL, const int* __restrict__ perm,
    short* __restrict__ P, float* __restrict__ lsumA,
    float* __restrict__ lsumB, float* __restrict__ Og)
{
    // SMEM: Ksh (single 64x128 tile, 16KB) | Vsh double (2x 64x128, 32KB)
    // epilogue slab = first 32KB of SMEM (all K/V reads done by then)
    __shared__ __align__(16) short SMEM[3 * 64 * 128];   // 49152 B
    __shared__ __align__(16) float biasSh[2][64];        //   512 B
    __shared__ float Lsum[4][32];                        //   512 B
    __shared__ int   permSh[64];                         //   256 B -> ~50.4 KB

    short* Ksh  = SMEM;                 // 64*128
    short* Vsh0 = SMEM + 8192;          // Vsh[buf] = Vsh0 + buf*8192

    const int tid  = threadIdx.x;
    const int lane = tid & 63;
    const int w    = tid >> 6;    // wave 0..3
    const int pair = w >> 1;      // q-strip: rows [pair*32, pair*32+32)
    const int half = w & 1;       // key-half within the 64-key tile (wave-uniform)
    const int l31  = lane & 31;
    const int hi   = lane >> 5;

    // lin 0..1023: xcd tag = lin&7 (L2 locality); rank: longest-first order.
    const int lin   = blockIdx.x;
    const int xcd   = lin & 7;
    const int rank  = lin >> 3;           // 0..127
    const int qj    = 31 - (rank >> 2);   // sorted job index, descending length
    const int sub   = rank & 3;
    const int bsel  = sub >> 1;
    const int khalf = sub & 1;
    const int b     = xcd * 2 + bsel;
    const int lo    = qj * BQ;

    const short* Kb_b = Kb  + (size_t)b * Kn * Dn;
    const short* Vt_b = Vtb + (size_t)b * DVn * Kn;
    const float* bias_b = biasg + b * Kn;
    float* Og_b = Og + (size_t)b * Qn * DVn;
    short* P_b  = P  + (size_t)b * Qn * DVn;

    if (tid < 64) permSh[tid] = perm[b * Qn + lo + tid];
    __syncthreads();

    // ---- DMA source pointers ----
    const short* ksp[4]; int kdo[4];
    const short* vsp[4]; int vdo[4];
#pragma unroll
    for (int i = 0; i < 4; ++i) {
        const int rl = w * 16 + i * 4 + (lane >> 4);       // K tile row 0..63
        const int ch = (lane & 15) ^ (rl & 15);
        ksp[i] = Kb_b + (size_t)rl * Dn + ch * 8;
        kdo[i] = (w * 16 + i * 4) * 128;
        const int rv = w * 16 + i * 4 + (lane >> 4);       // V tile row 0..63
        const int cc = (lane & 15) ^ (rv & 15);            // source chunk
        const int vv = 2 * rv + (cc >> 3);
        vsp[i] = Vt_b + (size_t)vv * Kn + (cc & 7) * 8;
        vdo[i] = (w * 16 + i * 4) * 128;
    }

    // ---- Q fragments (gathered via perm): [n=l31][k=kt*16+hi*8+j] ----
    const int qperm = permSh[pair * 32 + l31];
    bf16x8 qf[8];
    {
        const float* qrow = Qg + ((size_t)b * Qn + qperm) * Dn;
#pragma unroll
        for (int kt = 0; kt < 8; ++kt) {
            const float* p = qrow + kt * 16 + hi * 8;
            float4 x0 = *(const float4*)(p);
            float4 x1 = *(const float4*)(p + 4);
            bf16x8 f;
            f[0]=f2bf(x0.x); f[1]=f2bf(x0.y); f[2]=f2bf(x0.z); f[3]=f2bf(x0.w);
            f[4]=f2bf(x1.x); f[5]=f2bf(x1.y); f[6]=f2bf(x1.z); f[7]=f2bf(x1.w);
            qf[kt] = f;
        }
    }
    const int vlq = VL[b * Qn + qperm];
    // rows sorted ascending within the job -> max valid_len is the last row
    const int T    = (VL[b * Qn + permSh[63]] + BK - 1) >> 6;   // 1..32 tiles
    const int TL   = (T + 1) >> 1;
    const int kbeg = (khalf ? TL : 0) * BK;
    const int kend = (khalf ? T : TL) * BK;

    f32x16 Oacc[4];   // v = nt*32 + l31, all 128 v; keys restricted to own half
#pragma unroll
    for (int nt = 0; nt < 4; ++nt)
#pragma unroll
        for (int j = 0; j < 16; ++j) Oacc[nt][j] = 0.f;
    float psum = 0.f;
    const int kr = half * 32 + l31;

    if (kbeg < kend) {
        // prologue: DMA tile kbeg (K -> single Ksh; V/bias -> parity buffer)
        const int pb0 = (kbeg >> 6) & 1;
#pragma unroll
        for (int i = 0; i < 4; ++i) {
            gld16(ksp[i] + (size_t)kbeg * Dn, &Ksh[kdo[i]]);
            gld16(vsp[i] + kbeg,              &Vsh0[pb0 * 8192 + vdo[i]]);
        }
        if (w == 0) gld4(bias_b + kbeg + lane, &biasSh[pb0][0]);

        for (int k0k = kbeg; k0k < kend; k0k += BK) {
            const int buf = (k0k >> 6) & 1;
            const int nk  = k0k + BK;
            __syncthreads();   // vmcnt(0) drain: K/V/bias of k0k landed; prev readers done

            if (nk < kend) {   // V + bias: double-buffered, issue early
#pragma unroll
                for (int i = 0; i < 4; ++i)
                    gld16(vsp[i] + nk, &Vsh0[(buf ^ 1) * 8192 + vdo[i]]);
                if (w == 0) gld4(bias_b + nk + lane, &biasSh[buf ^ 1][0]);
            }

            float4 bv[4];
#pragma unroll
            for (int rq = 0; rq < 4; ++rq)
                bv[rq] = *(const float4*)&biasSh[buf][half * 32 + rq * 8 + hi * 4];

            // ---- S^T = K_half . Q^T : stream K frags from the single Ksh ----
            f32x16 Sv;
#pragma unroll
            for (int j = 0; j < 16; ++j) Sv[j] = 0.f;
#pragma unroll
            for (int kt = 0; kt < 8; ++kt) {
                bf16x8 kf = *(const bf16x8*)&Ksh[kr * 128 + (((kt*2 + hi) ^ (kr & 15)) * 8)];
                Sv = __builtin_amdgcn_mfma_f32_32x32x16_bf16(kf, qf[kt], Sv, 0, 0, 0);
            }

            // release Ksh: all waves' K (and bias) LDS reads are complete.
            // Raw barrier + lgkmcnt only -- V DMA above stays in flight.
            asm volatile("s_waitcnt lgkmcnt(0)" ::: "memory");
            __builtin_amdgcn_s_barrier();
            __builtin_amdgcn_sched_barrier(0);
            if (nk < kend) {   // K(next) into the single buffer; lands under PV
#pragma unroll
                for (int i = 0; i < 4; ++i)
                    gld16(ksp[i] + (size_t)nk * Dn, &Ksh[kdo[i]]);
            }

            // ---- softmax in exp2 domain (results back into Sv) ----
#pragma unroll
            for (int rq = 0; rq < 4; ++rq) {
#pragma unroll
                for (int r = 0; r < 4; ++r) {
                    const int reg = rq * 4 + r;
                    const int keyg = k0k + half * 32 + rq * 8 + hi * 4 + r;
                    float a = fmaf(Sv[reg], SC2, bv[rq][r]);
                    a = (keyg < vlq) ? a : -200.0f;
                    const float p = exp2_raw(a);
                    psum += p;
                    Sv[reg] = p;
                }
            }

            // ---- PV: C-layout -> A-layout via lane^32 exchange; 8 MFMA ----
            const short* vbuf = &Vsh0[buf * 8192];
#pragma unroll
            for (int kt = 0; kt < 2; ++kt) {
                unsigned kAx = __builtin_amdgcn_perm(__float_as_uint(Sv[(2*kt)*4+1]),
                                                     __float_as_uint(Sv[(2*kt)*4+0]), 0x07060302u);
                unsigned kAy = __builtin_amdgcn_perm(__float_as_uint(Sv[(2*kt)*4+3]),
                                                     __float_as_uint(Sv[(2*kt)*4+2]), 0x07060302u);
                unsigned kBx = __builtin_amdgcn_perm(__float_as_uint(Sv[(2*kt+1)*4+1]),
                                                     __float_as_uint(Sv[(2*kt+1)*4+0]), 0x07060302u);
                unsigned kBy = __builtin_amdgcn_perm(__float_as_uint(Sv[(2*kt+1)*4+3]),
                                                     __float_as_uint(Sv[(2*kt+1)*4+2]), 0x07060302u);
                const unsigned sx = hi ? kAx : kBx;
                const unsigned sy = hi ? kAy : kBy;
                const unsigned rx = __shfl_xor(sx, 32);
                const unsigned ry = __shfl_xor(sy, 32);
                uint4 au;
                au.x = hi ? rx : kAx;
                au.y = hi ? ry : kAy;
                au.z = hi ? kBx : rx;
                au.w = hi ? kBy : ry;
                const bf16x8 af = __builtin_bit_cast(bf16x8, au);
                const int kc = half * 4 + kt * 2 + hi;   // key-chunk within tile
#pragma unroll
                for (int nt = 0; nt < 4; ++nt) {
                    const int v  = nt * 32 + l31;
                    const int r  = v >> 1;
                    const int p  = ((v & 1) * 8 + kc) ^ (r & 15);
                    bf16x8 vf = *(const bf16x8*)&vbuf[r * 128 + p * 8];
                    Oacc[nt] = __builtin_amdgcn_mfma_f32_32x32x16_bf16(af, vf, Oacc[nt], 0, 0, 0);
                }
            }
        }
    }

    // ---- epilogue: combine key-halves across wave pairs via LDS ----
    psum += __shfl_xor(psum, 32);
    if (lane < 32) Lsum[w][l31] = psum;
    __syncthreads();   // all waves done with SMEM (and DMA drained) -> reuse as slab

    float* slab = (float*)SMEM;    // 32KB needed, 48KB available
    {
        float* dst0 = slab + ((pair * 2 + (1 - half)) * 2 + 0) * 1024;
        float* dst1 = slab + ((pair * 2 + (1 - half)) * 2 + 1) * 1024;
        if (half == 0) {
            DUMP_ACC(Oacc[2], dst0);
            DUMP_ACC(Oacc[3], dst1);
        } else {
            DUMP_ACC(Oacc[0], dst0);
            DUMP_ACC(Oacc[1], dst1);
        }
    }
    __syncthreads();

    // per-row denominator partial for this K-half (plain store, no atomics)
    if (tid < 64) {
        const float ls = Lsum[(tid >> 5) * 2][tid & 31]
                       + Lsum[(tid >> 5) * 2 + 1][tid & 31];
        (khalf ? lsumB : lsumA)[b * Qn + permSh[tid]] = ls;
    }

    if (khalf == 0) {
        const float* src0 = slab + ((pair * 2 + half) * 2 + 0) * 1024;
        const float* src1 = slab + ((pair * 2 + half) * 2 + 1) * 1024;
        if (half == 0) {
            STORE_F(Oacc[0], src0, 0);
            STORE_F(Oacc[1], src1, 32);
        } else {
            STORE_F(Oacc[2], src0, 64);
            STORE_F(Oacc[3], src1, 96);
        }
    } else {
        const float* src0 = slab + ((pair * 2 + half) * 2 + 0) * 1024;
        const float* src1 = slab + ((pair * 2 + half) * 2 + 1) * 1024;
        if (half == 0) {
            STORE_H(Oacc[0], src0, 0);
            STORE_H(Oacc[1], src1, 32);
        } else {
            STORE_H(Oacc[2], src0, 64);
            STORE_H(Oacc[3], src1, 96);
        }
    }
}

// ---------- normalize: Og = (Og + P) / (lA + lB) ----------
__global__ __launch_bounds__(256) void norm_kernel(const short* __restrict__ P,
                                                   const float* __restrict__ lA,
                                                   const float* __restrict__ lB,
                                                   float* __restrict__ Og) {
    const int t = blockIdx.x * 256 + threadIdx.x;     // 0..262143
    const size_t base = (size_t)t * 16;               // 16 floats, one row chunk
    const int row = t >> 3;                           // 8 threads per 128-col row
    const float inv = 1.f / (lA[row] + lB[row]);
    float4* og4 = (float4*)(Og + base);
    const bf16x8* p8 = (const bf16x8*)(P + base);
#pragma unroll
    for (int i = 0; i < 2; ++i) {
        const bf16x8 ph = p8[i];
        float4 a = og4[i * 2], c = og4[i * 2 + 1];
        a.x = (a.x + bf2f(ph[0])) * inv;
        a.y = (a.y + bf2f(ph[1])) * inv;
        a.z = (a.z + bf2f(ph[2])) * inv;
        a.w = (a.w + bf2f(ph[3])) * inv;
        c.x = (c.x + bf2f(ph[4])) * inv;
        c.y = (c.y + bf2f(ph[5])) * inv;
        c.z = (c.z + bf2f(ph[6])) * inv;
        c.w = (c.w + bf2f(ph[7])) * inv;
        og4[i * 2]     = a;
        og4[i * 2 + 1] = c;
    }
}

extern "C" void kernel_launch(void* const* d_in, const int* in_sizes, int n_in,
                              void* d_out, int out_size, void* d_ws, size_t ws_size,
                              hipStream_t stream) {
    const float* Qg = (const float*)d_in[0];
    const float* Kg = (const float*)d_in[1];
    const float* Vg = (const float*)d_in[2];
    const int*   VL = (const int*)d_in[3];
    float* Og = (float*)d_out;
    (void)ws_size;

    // ws: Kb bf16 8MB | Vtb bf16 8MB | bias f32 128KB | perm int 128KB
    //     | lsumA f32 128KB | lsumB f32 128KB | P bf16 8MB   (~24.5MB)
    char* ws = (char*)d_ws;
    const size_t base = (size_t)Bn * Kn * Dn * 4;     // 16MB
    short* Kb    = (short*)(ws);
    short* Vtb   = (short*)(ws + (size_t)Bn * Kn * Dn * 2);
    float* bias  = (float*)(ws + base);
    int*   perm  = (int*)  (ws + base + 131072);
    float* lsumA = (float*)(ws + base + 262144);
    float* lsumB = (float*)(ws + base + 393216);
    short* P     = (short*)(ws + base + 524288);

    prep_kv<<<dim3(1552), dim3(256), 0, stream>>>(Kg, Vg, VL, Kb, Vtb, bias, perm);
    attn_kernel<<<dim3(1024), dim3(256), 0, stream>>>(Qg, Kb, Vtb, bias, VL,
                                                      perm, P, lsumA, lsumB, Og);
    norm_kernel<<<dim3(1024), dim3(256), 0, stream>>>(P, lsumA, lsumB, Og);
}

// Round 12
// 143.987 us; speedup vs baseline: 1.0858x; 1.0858x over previous
//
#include <hip/hip_runtime.h>

// B=16, Q=2048, K=2048, D=128, DV=128
// out[b,q,:] = softmax_k((q.k - 0.5||k||^2)/sqrt(192), mask k>=valid_len) @ V
// R20: equal-length blocks by construction. 11 rounds established: CU thruput
// ~1 tile/us with 2 co-resident blocks; sorted work = 33 tiles/CU ideal; all
// pairing/queue/merge/occupancy attacks failed (unpredictable placement, L2
// scatter, protocol cost, register spill). This round: pair sorted job p with
// 31-p (concat C=T_lo+T_hi ~ 33 tiles, ~constant); block A = all of job p
// (DIRECT normalized write, exact R14 path) + prefix [0,s) of job 31-p (raw
// fp32 partial -> Og + lsumA); block B = suffix [s,T_hi) (bf16 partial -> P +
// lsumB; s==0 -> B owns whole job -> DIRECT). Disjoint destinations (R18's
// proven scheme), no atomics/flags. norm combines rows with lsumA>0 only
// (low range starts at k=0, vl>=1 -> lsumA>0 iff split row; prep zeroes
// lsums). Every block ~16-17 tiles; grid 512; LDS 66.8KB forces exactly
// 2 blocks/CU -> balance holds under ANY dispatch.

#define Bn   16
#define Qn   2048
#define Kn   2048
#define Dn   128
#define DVn  128
#define BQ   64
#define BK   64

// (1/sqrt(192)) * log2(e) : softmax computed as 2^(qk*SC2 + bias2)
#define SC2 0.10411754f

typedef short bf16x4 __attribute__((ext_vector_type(4)));
typedef short bf16x8 __attribute__((ext_vector_type(8)));
typedef float f32x16 __attribute__((ext_vector_type(16)));

__device__ __forceinline__ short f2bf(float x) {   // RNE
    union { float f; unsigned u; } v; v.f = x;
    unsigned r = (v.u + 0x7fffu + ((v.u >> 16) & 1u)) >> 16;
    return (short)r;
}
__device__ __forceinline__ float bf2f(short h) {
    union { unsigned u; float f; } v; v.u = ((unsigned)(unsigned short)h) << 16;
    return v.f;
}

typedef const __attribute__((address_space(1))) void* gas_t;
typedef __attribute__((address_space(3))) void* las_t;
__device__ __forceinline__ void gld16(const void* g, void* l) {
    __builtin_amdgcn_global_load_lds((gas_t)g, (las_t)l, 16, 0, 0);
}
__device__ __forceinline__ void gld4(const void* g, void* l) {
    __builtin_amdgcn_global_load_lds((gas_t)g, (las_t)l, 4, 0, 0);
}
__device__ __forceinline__ float exp2_raw(float a) {  // D = 2^S0
    float p;
    asm("v_exp_f32 %0, %1" : "=v"(p) : "v"(a));
    return p;
}

// ---------- preprocess: K/V convert + q-sort + lsum zeroing ----------
__global__ __launch_bounds__(256) void prep_kv(const float* __restrict__ Kg,
                                               const float* __restrict__ Vg,
                                               const int* __restrict__ VLg,
                                               short* __restrict__ Kb,
                                               short* __restrict__ Vtb,
                                               float* __restrict__ biasg,
                                               int* __restrict__ perm,
                                               float* __restrict__ lsumA,
                                               float* __restrict__ lsumB) {
    const int tid = threadIdx.x;
    if (blockIdx.x < 1024) {
        // ---- K path: 32 rows (b*Kn+row flat) per block, fully coalesced ----
        const int rowbase = blockIdx.x * 32;
        const float* src = Kg + (size_t)rowbase * Dn;
        short*       dst = Kb + (size_t)rowbase * Dn;
#pragma unroll
        for (int p = 0; p < 4; ++p) {
            const int idx = p * 1024 + tid * 4;     // flat float index
            float4 x = *(const float4*)(src + idx);
            bf16x4 h;
            h[0] = f2bf(x.x); h[1] = f2bf(x.y); h[2] = f2bf(x.z); h[3] = f2bf(x.w);
            *(bf16x4*)(dst + idx) = h;
            float ssq = x.x*x.x + x.y*x.y + x.z*x.z + x.w*x.w;
            ssq += __shfl_xor(ssq, 1);
            ssq += __shfl_xor(ssq, 2);
            ssq += __shfl_xor(ssq, 4);
            ssq += __shfl_xor(ssq, 8);
            ssq += __shfl_xor(ssq, 16);
            if ((tid & 31) == 0)
                biasg[rowbase + p * 8 + (tid >> 5)] = -0.5f * ssq * SC2;
        }
    } else if (blockIdx.x < 1536) {
        // ---- V path: transpose one [64 k][128 v] tile to plain V^T bf16 ----
        const int blk = blockIdx.x - 1024;
        const int b  = blk >> 5;
        const int k0 = (blk & 31) * 64;
        __shared__ short Ls[64 * 128];
#pragma unroll
        for (int p = 0; p < 8; ++p) {
            const int kk = p * 8 + (tid >> 5);      // tile row 0..63
            const int v0 = (tid & 31) * 4;
            float4 x = *(const float4*)(Vg + ((size_t)b * Kn + k0 + kk) * DVn + v0);
            bf16x4 h;
            h[0] = f2bf(x.x); h[1] = f2bf(x.y); h[2] = f2bf(x.z); h[3] = f2bf(x.w);
            const int vs = v0 ^ ((kk & 15) << 3);   // keeps 4-short alignment
            *(bf16x4*)&Ls[kk * 128 + vs] = h;
        }
        __syncthreads();
        const int v = tid >> 1;
        const int h = (tid & 1) * 32;
        short* dst = Vtb + ((size_t)b * DVn + v) * Kn + k0 + h;
#pragma unroll
        for (int j4 = 0; j4 < 4; ++j4) {
            bf16x8 o;
#pragma unroll
            for (int j = 0; j < 8; ++j) {
                const int kk = h + j4 * 8 + j;
                o[j] = Ls[kk * 128 + (v ^ ((kk & 15) << 3))];
            }
            *(bf16x8*)(dst + j4 * 8) = o;
        }
    } else {
        // ---- sort path: counting sort of 2048 q-rows by valid_len, batch b ----
        const int b = blockIdx.x - 1536;
        __shared__ int hist[2048];
        __shared__ int part[256];
        int vq[8];
#pragma unroll
        for (int i = 0; i < 8; ++i) {
            hist[i * 256 + tid] = 0;
            lsumA[b * Qn + i * 256 + tid] = 0.f;    // skip-markers for norm
            lsumB[b * Qn + i * 256 + tid] = 0.f;
        }
        __syncthreads();
#pragma unroll
        for (int i = 0; i < 8; ++i) {
            vq[i] = VLg[b * Qn + i * 256 + tid];    // 1..2048
            atomicAdd(&hist[vq[i] - 1], 1);
        }
        __syncthreads();
        // exclusive scan over 2048 bins (8 per thread + block scan)
        int lex[8]; int s = 0;
#pragma unroll
        for (int j = 0; j < 8; ++j) { lex[j] = s; s += hist[tid * 8 + j]; }
        part[tid] = s;
        __syncthreads();
        for (int off = 1; off < 256; off <<= 1) {
            int v = (tid >= off) ? part[tid - off] : 0;
            __syncthreads();
            part[tid] += v;
            __syncthreads();
        }
        const int excl = part[tid] - s;
#pragma unroll
        for (int j = 0; j < 8; ++j) hist[tid * 8 + j] = excl + lex[j];
        __syncthreads();
        // scatter: ascending positions by valid_len
#pragma unroll
        for (int i = 0; i < 8; ++i) {
            const int pos = atomicAdd(&hist[vq[i] - 1], 1);
            perm[b * Qn + pos] = i * 256 + tid;
        }
    }
}

// epilogue helpers with LITERAL accumulator indices (no runtime Oacc[] index)
#define DUMP_ACC(ACC, DST)                                            \
    {                                                                 \
        _Pragma("unroll")                                             \
        for (int reg = 0; reg < 16; ++reg) {                          \
            const int row = (reg & 3) + 8 * (reg >> 2) + 4 * hi;      \
            (DST)[row * 32 + l31] = (ACC)[reg];                       \
        }                                                             \
    }
// normalized fp32 -> Og (single-covered jobs)
#define STORE_ACC(ACC, SRC, COLBASE)                                  \
    {                                                                 \
        _Pragma("unroll")                                             \
        for (int reg = 0; reg < 16; ++reg) {                          \
            const int row = (reg & 3) + 8 * (reg >> 2) + 4 * hi;      \
            const float o = (ACC)[reg] + (SRC)[row * 32 + l31];       \
            Og_b[(size_t)permSh[pair * 32 + row] * DVn + (COLBASE) + l31] \
                = o * invl[reg];                                      \
        }                                                             \
    }
// raw fp32 partial -> Og (low part of split job)
#define STORE_F(ACC, SRC, COLBASE)                                    \
    {                                                                 \
        _Pragma("unroll")                                             \
        for (int reg = 0; reg < 16; ++reg) {                          \
            const int row = (reg & 3) + 8 * (reg >> 2) + 4 * hi;      \
            Og_b[(size_t)permSh[pair * 32 + row] * DVn + (COLBASE) + l31] \
                = (ACC)[reg] + (SRC)[row * 32 + l31];                 \
        }                                                             \
    }
// raw bf16 partial -> P (high part of split job)
#define STORE_H(ACC, SRC, COLBASE)                                    \
    {                                                                 \
        _Pragma("unroll")                                             \
        for (int reg = 0; reg < 16; ++reg) {                          \
            const int row = (reg & 3) + 8 * (reg >> 2) + 4 * hi;      \
            P_b[(size_t)permSh[pair * 32 + row] * DVn + (COLBASE) + l31] \
                = f2bf((ACC)[reg] + (SRC)[row * 32 + l31]);           \
        }                                                             \
    }

// ---------- main attention kernel: equal-length blocks, grid 512 ----------
__global__ __launch_bounds__(256, 2) void attn_kernel(
    const float* __restrict__ Qg, const short* __restrict__ Kb,
    const short* __restrict__ Vtb, const float* __restrict__ biasg,
    const int* __restrict__ VL, const int* __restrict__ perm,
    short* __restrict__ P, float* __restrict__ lsumA,
    float* __restrict__ lsumB, float* __restrict__ Og)
{
    __shared__ __align__(16) short Ksh[2][64 * 128];   // 32768 B (epilogue: float slab)
    __shared__ __align__(16) short Vsh[2][64 * 128];   // 32768 B
    __shared__ __align__(16) float biasSh[2][64];      //   512 B
    __shared__ float Lsum[4][32];                      //   512 B
    __shared__ int   permSh[64];                       //   256 B -> 66816 B

    const int tid  = threadIdx.x;
    const int lane = tid & 63;
    const int w    = tid >> 6;    // wave 0..3
    const int pair = w >> 1;      // q-strip: rows [pair*32, pair*32+32)
    const int half = w & 1;       // key-half within the 64-key tile (wave-uniform)
    const int l31  = lane & 31;
    const int hi   = lane >> 5;

    // lin 0..511: xcd = lin&7 (L2 locality); fields: h_(A/B), bsel, pairI
    const int lin   = blockIdx.x;
    const int xcd   = lin & 7;
    const int r6    = lin >> 3;           // 0..63
    const int h_    = r6 & 1;
    const int bsel  = (r6 >> 1) & 1;
    const int pairI = r6 >> 2;            // 0..15
    const int b     = xcd * 2 + bsel;
    const int jLo   = pairI;
    const int jHi   = 31 - pairI;

    const short* Kb_b = Kb  + (size_t)b * Kn * Dn;
    const short* Vt_b = Vtb + (size_t)b * DVn * Kn;
    const float* bias_b = biasg + b * Kn;
    float* Og_b = Og + (size_t)b * Qn * DVn;
    short* P_b  = P  + (size_t)b * Qn * DVn;

    // job lengths (rows sorted ascending -> last row holds the max)
    const int Tlo = (VL[b * Qn + perm[b * Qn + jLo * BQ + 63]] + 63) >> 6;
    const int Thi = (VL[b * Qn + perm[b * Qn + jHi * BQ + 63]] + 63) >> 6;
    const int mid = (Tlo + Thi + 1) >> 1;
    const int s   = mid - Tlo;            // >= 0 (Tlo <= Thi)

    // phase table: {job, kbeg(tiles), kend(tiles), mode 0=DIRECT 1=LOW 2=HIGH}
    int nph, jqv[2], kbv[2], kev[2], mdv[2];
    if (h_ == 0) {
        jqv[0] = jLo; kbv[0] = 0; kev[0] = Tlo; mdv[0] = 0;
        jqv[1] = jHi; kbv[1] = 0; kev[1] = s;   mdv[1] = 1;
        nph = (s > 0) ? 2 : 1;
    } else {
        jqv[0] = jHi; kbv[0] = s; kev[0] = Thi; mdv[0] = (s == 0) ? 0 : 2;
        jqv[1] = jHi; kbv[1] = 0; kev[1] = 0;   mdv[1] = 0;
        nph = 1;
    }

    // ---- DMA source pointers (job-independent) ----
    const short* ksp[4]; int kdo[4];
    const short* vsp[4]; int vdo[4];
#pragma unroll
    for (int i = 0; i < 4; ++i) {
        const int rl = w * 16 + i * 4 + (lane >> 4);       // K tile row 0..63
        const int ch = (lane & 15) ^ (rl & 15);
        ksp[i] = Kb_b + (size_t)rl * Dn + ch * 8;
        kdo[i] = (w * 16 + i * 4) * 128;
        const int rv = rl;
        const int cc = (lane & 15) ^ (rv & 15);            // source chunk
        const int vv = 2 * rv + (cc >> 3);
        vsp[i] = Vt_b + (size_t)vv * Kn + (cc & 7) * 8;
        vdo[i] = (w * 16 + i * 4) * 128;
    }
    const int kr = half * 32 + l31;

#pragma unroll 1
    for (int phI = 0; phI < nph; ++phI) {
        const int jq   = jqv[phI];
        const int kbeg = kbv[phI] * BK;
        const int kend = kev[phI] * BK;
        const int mode = mdv[phI];

        __syncthreads();                   // prior phase slab/LDS fully done
        if (tid < 64) permSh[tid] = perm[b * Qn + jq * BQ + tid];
        __syncthreads();

        // ---- Q fragments (gathered via perm) ----
        const int qperm = permSh[pair * 32 + l31];
        bf16x8 qf[8];
        {
            const float* qrow = Qg + ((size_t)b * Qn + qperm) * Dn;
#pragma unroll
            for (int kt = 0; kt < 8; ++kt) {
                const float* p = qrow + kt * 16 + hi * 8;
                float4 x0 = *(const float4*)(p);
                float4 x1 = *(const float4*)(p + 4);
                bf16x8 f;
                f[0]=f2bf(x0.x); f[1]=f2bf(x0.y); f[2]=f2bf(x0.z); f[3]=f2bf(x0.w);
                f[4]=f2bf(x1.x); f[5]=f2bf(x1.y); f[6]=f2bf(x1.z); f[7]=f2bf(x1.w);
                qf[kt] = f;
            }
        }
        const int vlq = VL[b * Qn + qperm];

        f32x16 Oacc[4];
#pragma unroll
        for (int nt = 0; nt < 4; ++nt)
#pragma unroll
            for (int j = 0; j < 16; ++j) Oacc[nt][j] = 0.f;
        float psum = 0.f;

        {
            // prologue: DMA tile kbeg into its parity buffer
            const int pb0 = (kbeg >> 6) & 1;
#pragma unroll
            for (int i = 0; i < 4; ++i) {
                gld16(ksp[i] + (size_t)kbeg * Dn, &Ksh[pb0][kdo[i]]);
                gld16(vsp[i] + kbeg,              &Vsh[pb0][vdo[i]]);
            }
            if (w == 0) gld4(bias_b + kbeg + lane, &biasSh[pb0][0]);

            for (int k0k = kbeg; k0k < kend; k0k += BK) {
                const int buf = (k0k >> 6) & 1;
                __syncthreads();   // drains vmcnt(0): tile ready; prev readers done

                if (k0k + BK < kend) {
                    const int nk = k0k + BK;
#pragma unroll
                    for (int i = 0; i < 4; ++i) {
                        gld16(ksp[i] + (size_t)nk * Dn, &Ksh[buf ^ 1][kdo[i]]);
                        gld16(vsp[i] + nk,              &Vsh[buf ^ 1][vdo[i]]);
                    }
                    if (w == 0) gld4(bias_b + nk + lane, &biasSh[buf ^ 1][0]);
                }

                float4 bv[4];
#pragma unroll
                for (int rq = 0; rq < 4; ++rq)
                    bv[rq] = *(const float4*)&biasSh[buf][half * 32 + rq * 8 + hi * 4];

                // ---- S^T = K_half . Q^T : one 32x32 tile per wave (8 MFMA) ----
                const short* kbuf = Ksh[buf];
                f32x16 Sv;
#pragma unroll
                for (int j = 0; j < 16; ++j) Sv[j] = 0.f;
#pragma unroll
                for (int kt = 0; kt < 8; ++kt) {
                    bf16x8 kf = *(const bf16x8*)&kbuf[kr * 128 + (((kt*2 + hi) ^ (kr & 15)) * 8)];
                    Sv = __builtin_amdgcn_mfma_f32_32x32x16_bf16(kf, qf[kt], Sv, 0, 0, 0);
                }

                // ---- softmax in exp2 domain ----
#pragma unroll
                for (int rq = 0; rq < 4; ++rq) {
#pragma unroll
                    for (int r = 0; r < 4; ++r) {
                        const int reg = rq * 4 + r;
                        const int keyg = k0k + half * 32 + rq * 8 + hi * 4 + r;
                        float a = fmaf(Sv[reg], SC2, bv[rq][r]);
                        a = (keyg < vlq) ? a : -200.0f;
                        const float p = exp2_raw(a);
                        psum += p;
                        Sv[reg] = p;
                    }
                }

                // ---- PV: C-layout -> A-layout via lane^32 exchange; 8 MFMA ----
                const short* vbuf = Vsh[buf];
#pragma unroll
                for (int kt = 0; kt < 2; ++kt) {
                    unsigned kAx = __builtin_amdgcn_perm(__float_as_uint(Sv[(2*kt)*4+1]),
                                                         __float_as_uint(Sv[(2*kt)*4+0]), 0x07060302u);
                    unsigned kAy = __builtin_amdgcn_perm(__float_as_uint(Sv[(2*kt)*4+3]),
                                                         __float_as_uint(Sv[(2*kt)*4+2]), 0x07060302u);
                    unsigned kBx = __builtin_amdgcn_perm(__float_as_uint(Sv[(2*kt+1)*4+1]),
                                                         __float_as_uint(Sv[(2*kt+1)*4+0]), 0x07060302u);
                    unsigned kBy = __builtin_amdgcn_perm(__float_as_uint(Sv[(2*kt+1)*4+3]),
                                                         __float_as_uint(Sv[(2*kt+1)*4+2]), 0x07060302u);
                    const unsigned sx = hi ? kAx : kBx;
                    const unsigned sy = hi ? kAy : kBy;
                    const unsigned rx = __shfl_xor(sx, 32);
                    const unsigned ry = __shfl_xor(sy, 32);
                    uint4 au;
                    au.x = hi ? rx : kAx;
                    au.y = hi ? ry : kAy;
                    au.z = hi ? kBx : rx;
                    au.w = hi ? kBy : ry;
                    const bf16x8 af = __builtin_bit_cast(bf16x8, au);
                    const int kc = half * 4 + kt * 2 + hi;   // key-chunk within tile
#pragma unroll
                    for (int nt = 0; nt < 4; ++nt) {
                        const int v  = nt * 32 + l31;
                        const int r  = v >> 1;
                        const int p  = ((v & 1) * 8 + kc) ^ (r & 15);
                        bf16x8 vf = *(const bf16x8*)&vbuf[r * 128 + p * 8];
                        Oacc[nt] = __builtin_amdgcn_mfma_f32_32x32x16_bf16(af, vf, Oacc[nt], 0, 0, 0);
                    }
                }
            }
        }

        // ---- epilogue: combine key-halves across wave pairs via LDS ----
        psum += __shfl_xor(psum, 32);
        if (lane < 32) Lsum[w][l31] = psum;
        __syncthreads();   // all waves done reading Ksh/Vsh -> safe to reuse Ksh

        float* slab = (float*)&Ksh[0][0];
        {
            float* dst0 = slab + ((pair * 2 + (1 - half)) * 2 + 0) * 1024;
            float* dst1 = slab + ((pair * 2 + (1 - half)) * 2 + 1) * 1024;
            if (half == 0) {
                DUMP_ACC(Oacc[2], dst0);
                DUMP_ACC(Oacc[3], dst1);
            } else {
                DUMP_ACC(Oacc[0], dst0);
                DUMP_ACC(Oacc[1], dst1);
            }
        }
        __syncthreads();

        const float* src0 = slab + ((pair * 2 + half) * 2 + 0) * 1024;
        const float* src1 = slab + ((pair * 2 + half) * 2 + 1) * 1024;

        if (mode == 0) {
            // single-covered job: full denominator available -> normalize
            float invl[16];
#pragma unroll
            for (int rq = 0; rq < 4; ++rq)
#pragma unroll
                for (int r = 0; r < 4; ++r) {
                    const int ql = r + 8 * rq + 4 * hi;
                    invl[rq*4+r] = 1.f / (Lsum[pair*2][ql] + Lsum[pair*2+1][ql]);
                }
            if (half == 0) {
                STORE_ACC(Oacc[0], src0, 0);
                STORE_ACC(Oacc[1], src1, 32);
            } else {
                STORE_ACC(Oacc[2], src0, 64);
                STORE_ACC(Oacc[3], src1, 96);
            }
        } else if (mode == 1) {
            // low part of split job: raw fp32 -> Og, denom -> lsumA
            if (tid < 64) {
                const float ls = Lsum[(tid >> 5) * 2][tid & 31]
                               + Lsum[(tid >> 5) * 2 + 1][tid & 31];
                lsumA[b * Qn + permSh[tid]] = ls;
            }
            if (half == 0) {
                STORE_F(Oacc[0], src0, 0);
                STORE_F(Oacc[1], src1, 32);
            } else {
                STORE_F(Oacc[2], src0, 64);
                STORE_F(Oacc[3], src1, 96);
            }
        } else {
            // high part of split job: raw bf16 -> P, denom -> lsumB
            if (tid < 64) {
                const float ls = Lsum[(tid >> 5) * 2][tid & 31]
                               + Lsum[(tid >> 5) * 2 + 1][tid & 31];
                lsumB[b * Qn + permSh[tid]] = ls;
            }
            if (half == 0) {
                STORE_H(Oacc[0], src0, 0);
                STORE_H(Oacc[1], src1, 32);
            } else {
                STORE_H(Oacc[2], src0, 64);
                STORE_H(Oacc[3], src1, 96);
            }
        }
    }
}

// ---------- normalize split rows: Og = (Og + P) / (lA + lB) ----------
__global__ __launch_bounds__(256) void norm_kernel(const short* __restrict__ P,
                                                   const float* __restrict__ lA,
                                                   const float* __restrict__ lB,
                                                   float* __restrict__ Og) {
    const int t = blockIdx.x * 256 + threadIdx.x;     // 0..262143
    const int row = t >> 3;                           // 8 threads per 128-col row
    const float la = lA[row];
    if (la == 0.f) return;                            // single-covered: done
    const float inv = 1.f / (la + lB[row]);
    const size_t base = (size_t)t * 16;
    float4* og4 = (float4*)(Og + base);
    const bf16x8* p8 = (const bf16x8*)(P + base);
#pragma unroll
    for (int i = 0; i < 2; ++i) {
        const bf16x8 ph = p8[i];
        float4 a = og4[i * 2], c = og4[i * 2 + 1];
        a.x = (a.x + bf2f(ph[0])) * inv;
        a.y = (a.y + bf2f(ph[1])) * inv;
        a.z = (a.z + bf2f(ph[2])) * inv;
        a.w = (a.w + bf2f(ph[3])) * inv;
        c.x = (c.x + bf2f(ph[4])) * inv;
        c.y = (c.y + bf2f(ph[5])) * inv;
        c.z = (c.z + bf2f(ph[6])) * inv;
        c.w = (c.w + bf2f(ph[7])) * inv;
        og4[i * 2]     = a;
        og4[i * 2 + 1] = c;
    }
}

extern "C" void kernel_launch(void* const* d_in, const int* in_sizes, int n_in,
                              void* d_out, int out_size, void* d_ws, size_t ws_size,
                              hipStream_t stream) {
    const float* Qg = (const float*)d_in[0];
    const float* Kg = (const float*)d_in[1];
    const float* Vg = (const float*)d_in[2];
    const int*   VL = (const int*)d_in[3];
    float* Og = (float*)d_out;
    (void)ws_size;

    // ws: Kb bf16 8MB | Vtb bf16 8MB | bias f32 128KB | perm int 128KB
    //     | lsumA f32 128KB | lsumB f32 128KB | P bf16 8MB   (~24.5MB)
    char* ws = (char*)d_ws;
    const size_t base = (size_t)Bn * Kn * Dn * 4;     // 16MB
    short* Kb    = (short*)(ws);
    short* Vtb   = (short*)(ws + (size_t)Bn * Kn * Dn * 2);
    float* bias  = (float*)(ws + base);
    int*   perm  = (int*)  (ws + base + 131072);
    float* lsumA = (float*)(ws + base + 262144);
    float* lsumB = (float*)(ws + base + 393216);
    short* P     = (short*)(ws + base + 524288);

    prep_kv<<<dim3(1552), dim3(256), 0, stream>>>(Kg, Vg, VL, Kb, Vtb, bias,
                                                  perm, lsumA, lsumB);
    attn_kernel<<<dim3(512), dim3(256), 0, stream>>>(Qg, Kb, Vtb, bias, VL,
                                                     perm, P, lsumA, lsumB, Og);
    norm_kernel<<<dim3(1024), dim3(256), 0, stream>>>(P, lsumA, lsumB, Og);
}